// Round 12
// baseline (134.240 us; speedup 1.0000x reference)
//
#include <hip/hip_runtime.h>
#include <stdint.h>

#define NSIMS 2048
#define NDIM 8
#define NE (NSIMS * NDIM)      // 16384 elements per timestep
#define NSTEPS 1500
#define TP1 (NSTEPS + 1)       // 1501 trajectory columns
#define TILE 128               // steps per lockstep tile
#define NTILE ((NSTEPS + TILE - 1) / TILE)   // 12 (last tile = 92 steps)
#define SENT 0x7fffffff

// ---------------- Threefry2x32-20 (exact JAX/Random123) ----------------
__device__ __forceinline__ void tf_block(uint32_t k0, uint32_t k1,
                                         uint32_t x0, uint32_t x1,
                                         uint32_t& o0, uint32_t& o1) {
  const uint32_t k2 = k0 ^ k1 ^ 0x1BD11BDAu;
  x0 += k0; x1 += k1;
#define TF_R(r) { x0 += x1; x1 = (x1 << (r)) | (x1 >> (32 - (r))); x1 ^= x0; }
  TF_R(13) TF_R(15) TF_R(26) TF_R(6)
  x0 += k1; x1 += k2 + 1u;
  TF_R(17) TF_R(29) TF_R(16) TF_R(24)
  x0 += k2; x1 += k0 + 2u;
  TF_R(13) TF_R(15) TF_R(26) TF_R(6)
  x0 += k0; x1 += k1 + 3u;
  TF_R(17) TF_R(29) TF_R(16) TF_R(24)
  x0 += k1; x1 += k2 + 4u;
  TF_R(13) TF_R(15) TF_R(26) TF_R(6)
  x0 += k2; x1 += k0 + 5u;
#undef TF_R
  o0 = x0; o1 = x1;
}

// bits -> uniform(-0.99999994, 1) -> sqrt(2)*erfinv, fast path (validated r10)
__device__ __forceinline__ float bits_to_normal(uint32_t bits) {
#pragma clang fp contract(off)
  const float LO = -0.99999994f;
  float f = __uint_as_float((bits >> 9) | 0x3F800000u) - 1.0f;  // [0,1)
  float u = f * 2.0f + LO;
  u = fmaxf(LO, u);
  float t = __builtin_fmaf(-u, u, 1.0f);   // 1 - u^2, single rounding
  float L = __log2f(t);                    // v_log_f32
  float p;
  if (L > -7.2134752f) {                   // w < 5
    float w = __builtin_fmaf(-0.69314718f, L, -2.5f);
    p = 3.97426059e-08f;
    p = 4.85462660e-07f + p * w;
    p = -4.98282379e-06f + p * w;
    p = -6.21053119e-06f + p * w;
    p = 3.09120051e-04f + p * w;
    p = -1.77303519e-03f + p * w;
    p = -5.90813402e-03f + p * w;
    p = 3.48802730e-01f + p * w;
    p = 2.12331454e+00f + p * w;
  } else {
    float w = sqrtf(-0.69314718f * L) - 3.0f;
    p = -2.83145880e-04f;
    p = 1.42765648e-04f + p * w;
    p = 1.90826058e-03f + p * w;
    p = -5.19501312e-03f + p * w;
    p = 8.11688966e-03f + p * w;
    p = -1.07797881e-02f + p * w;
    p = 1.33485786e-02f + p * w;
    p = 1.41658104e+00f + p * w;
    p = 4.00643424e+00f + p * w;
  }
  return p * u;   // == sqrt(2)*erfinv(u), sqrt(2) pre-folded
}

// ---------------- kernel 0: fold keys for all t ----------------
__global__ void k_fold(uint2* __restrict__ keys) {
  int t = blockIdx.x * blockDim.x + threadIdx.x;
  if (t >= NSTEPS) return;
  uint32_t o0, o1;
  tf_block(0u, 42u, 0u, (uint32_t)t, o0, o1);  // fold_in(key(42), t)
  keys[t] = make_uint2(o0, o1);
}

// ---------------- DPP 8-lane group ops ----------------
template <int CTRL>
__device__ __forceinline__ float dppf(float v) {
  int r = __builtin_amdgcn_update_dpp(0, __builtin_bit_cast(int, v), CTRL, 0xF, 0xF, true);
  return __builtin_bit_cast(float, r);
}
template <int CTRL>
__device__ __forceinline__ int dppi(int v) {
  return __builtin_amdgcn_update_dpp(0, v, CTRL, 0xF, 0xF, true);
}
// 0xB1=quad_perm[1,0,3,2](xor1) 0x4E=quad_perm[2,3,0,1](xor2)
// 0x1B=quad_perm[3,2,1,0](xor3) 0x141=row_half_mirror(xor7)

// one step, ungated (activeF==1 in live region; x1.0 is an exact identity).
// S-sum: 2 dependent DPP stages via parallel xor1/xor2/xor3 then xor7 —
// per-lane bit-identical (commuted operands only) to the validated butterfly.
#define STEP(ST, NZ)                                                    \
  {                                                                     \
    _Pragma("clang fp contract(off)")                                   \
    float x1 = dppf<0xB1>(act);                                         \
    float x2 = dppf<0x4E>(act);                                         \
    float x3 = dppf<0x1B>(act);                                         \
    float t1 = act + x1;                                                \
    float t2 = x2 + x3;                                                 \
    float Q = t1 + t2;                                                  \
    float S = Q + dppf<0x141>(Q);                                       \
    const float rec = (S * -0.1f) * 7.0f;   /* sum(act@gamma, axis=1) */\
    float a_ = inp - 0.1f * pre;                                        \
    float b_ = a_ + rec;                                                \
    pre = pre + b_ * 0.01f;                                             \
    pre = pre + (NZ) * 0.031622776601683793f; /* float(sqrt(0.001)) */  \
    act = fmaxf(pre, 0.0f);                                             \
    fc = (act >= 1.0f) ? (((ST) < fc) ? (ST) : fc) : fc;                \
    ptile[ST][lane] = pre;                                              \
  }

// ---------------- fused producer/consumer megakernel ----------------
// Block = 64 elements (8 sims), 8 waves. Wave 0: ungated recurrence ->
// LDS ptile; tile-end crossing rollback; frozen state published via
// sfroz/spre (prev-tile semantics -> race-free masked store).
// Waves 1..7: threefry noise for tile k+1 into LDS ring (rolled loop,
// 1-ahead key pipeline). Coalesced masked store each tile.
__global__ void __launch_bounds__(512) k_fused(const float* __restrict__ input,
                                               const uint2* __restrict__ keys,
                                               float* __restrict__ out) {
  __shared__ float ring[2][TILE][64];   // 64 KB noise double-buffer
  __shared__ float ptile[TILE][65];     // 33 KB pre tile (tau x e)
  __shared__ float spre[64];
  __shared__ float sfroz[64];
  __shared__ int sfz;
  const int tid = threadIdx.x;
  const int wid = tid >> 6;          // 0..7
  const int lane = tid & 63;
  const int e0 = (int)blockIdx.x << 6;
  const int e = e0 + lane;
  const size_t actoff = (size_t)NE * TP1;

  if (tid == 0) sfz = SENT;

  float pre = 0.0f, act = 0.0f, inp = 0.0f, spreR = 0.0f;
  int actv = 1;
  if (wid == 0) {
    inp = input[e];
    const size_t rowo = (size_t)e * TP1;
    out[rowo] = 0.0f;                  // tau = 0 zeros
    out[actoff + rowo] = 0.0f;
  } else {
    // prologue: produce tile 0 (rolled, 1-ahead key pipeline)
    int j = wid - 1;
    uint2 fk = keys[j];
    for (; j < TILE; j += 7) {
      const int jn = j + 7;
      uint2 fkn = (jn < TILE) ? keys[jn] : fk;
      uint32_t o0, o1;
      tf_block(fk.x, fk.y, 0u, (uint32_t)e, o0, o1);
      ring[0][j][lane] = bits_to_normal(o0 ^ o1);
      fk = fkn;
    }
  }
  __syncthreads();

  int fz = SENT;
  for (int k = 0; k < NTILE; ++k) {
    const int par = k & 1;
    const int base = k * TILE;
    const int nst = (NSTEPS - base < TILE) ? (NSTEPS - base) : TILE;
    if (wid == 0) {
      // publish frozen state as of END OF PREVIOUS tile (store reads after
      // barrier -> exactly "frozen before this tile" semantics, no race)
      sfroz[lane] = actv ? 0.0f : 1.0f;
      spre[lane] = spreR;
      int fc = TILE;   // tile-local first-crossing step (lane-local)
      if (nst == TILE) {
#pragma unroll 1
        for (int ch = 0; ch < TILE / 32; ++ch) {
          float nz[32];
#pragma unroll
          for (int j = 0; j < 32; ++j) nz[j] = ring[par][ch * 32 + j][lane];
#pragma unroll
          for (int j = 0; j < 32; ++j) STEP(ch * 32 + j, nz[j])
        }
      } else {
#pragma unroll 1
        for (int ch = 0; ch < TILE / 32; ++ch) {
          float nz[32];
#pragma unroll
          for (int j = 0; j < 32; ++j) nz[j] = ring[par][ch * 32 + j][lane];
#pragma unroll
          for (int j = 0; j < 32; ++j) {
            const int st = ch * 32 + j;
            if (st >= nst) break;
            STEP(st, nz[j])
          }
        }
      }
      // tile-end crossing resolution (off hot path)
      int c = fc;
      { int t_ = dppi<0xB1>(c);  c = (t_ < c) ? t_ : c; }
      { int t_ = dppi<0x4E>(c);  c = (t_ < c) ? t_ : c; }
      { int t_ = dppi<0x141>(c); c = (t_ < c) ? t_ : c; }
      if (actv && c < TILE) {
        const float fpre = ptile[c][lane];   // pre at crossing step (valid)
        for (int s = c + 1; s < TILE; ++s) ptile[s][lane] = fpre;
        spreR = fpre;
        actv = 0;
      }
      if (__ballot(actv != 0) == 0ull) {   // all 8 sims frozen
        spre[lane] = spreR;                // fresh values for tail fill
        if (lane == 0) sfz = base + nst + 1;
      }
    } else {
      // produce tile k+1 (rolled, 1-ahead key pipeline)
      const int nb = base + TILE;
      int j = wid - 1;
      if (nb + j < NSTEPS) {
        uint2 fk = keys[nb + j];
        for (; j < TILE && nb + j < NSTEPS; j += 7) {
          const int tn = nb + j + 7;
          uint2 fkn = (j + 7 < TILE && tn < NSTEPS) ? keys[tn] : fk;
          uint32_t o0, o1;
          tf_block(fk.x, fk.y, 0u, (uint32_t)e, o0, o1);
          ring[par ^ 1][j][lane] = bits_to_normal(o0 ^ o1);
          fk = fkn;
        }
      }
    }
    __syncthreads();
    // masked coalesced store: wave w owns e-rows w*8..w*8+7, lanes = tau
    {
      float fm[8], sv[8];
#pragma unroll
      for (int ee = 0; ee < 8; ++ee) {
        const int el = (wid << 3) + ee;
        fm[ee] = sfroz[el];
        sv[ee] = spre[el];
      }
#pragma unroll
      for (int tb = 0; tb < TILE / 64; ++tb) {
        const int ln = nst - tb * 64;
        if (lane < ln) {
          const int tau = base + 1 + tb * 64 + lane;
#pragma unroll
          for (int ee = 0; ee < 8; ++ee) {
            const int el = (wid << 3) + ee;
            float p = ptile[tb * 64 + lane][el];
            p = (fm[ee] > 0.0f) ? sv[ee] : p;
            const size_t o = (size_t)(e0 + el) * TP1 + (size_t)tau;
            out[o] = p;
            out[actoff + o] = fmaxf(p, 0.0f);   // act == relu(pre)
          }
        }
      }
    }
    if (sfz != SENT) { fz = sfz; break; }   // uniform exit (read after barrier)
    __syncthreads();                        // protect ptile/ring reuse
  }

  if (fz <= NSTEPS) {
    // post-freeze constant tail, coalesced (lanes over tau)
#pragma unroll
    for (int ee = 0; ee < 8; ++ee) {
      const int el = (wid << 3) + ee;
      const float p = spre[el];
      const float a = fmaxf(p, 0.0f);
      const size_t ro = (size_t)(e0 + el) * TP1;
      for (int tau = fz + lane; tau <= NSTEPS; tau += 64) {
        out[ro + (size_t)tau] = p;
        out[actoff + ro + (size_t)tau] = a;
      }
    }
  }
}

extern "C" void kernel_launch(void* const* d_in, const int* in_sizes, int n_in,
                              void* d_out, int out_size, void* d_ws, size_t ws_size,
                              hipStream_t stream) {
  const float* input = (const float*)d_in[0];
  float* out = (float*)d_out;
  uint2* keys = (uint2*)d_ws;   // 1500 * 8 B = 12 KB
  if (ws_size < NSTEPS * sizeof(uint2)) return;

  k_fold<<<dim3((NSTEPS + 255) / 256), dim3(256), 0, stream>>>(keys);
  k_fused<<<dim3(NSIMS / 8), dim3(512), 0, stream>>>(input, keys, out);
}

// Round 13
// 133.969 us; speedup vs baseline: 1.0020x; 1.0020x over previous
//
#include <hip/hip_runtime.h>
#include <stdint.h>

#define NSIMS 2048
#define NDIM 8
#define NE (NSIMS * NDIM)      // 16384 elements per timestep
#define NSTEPS 1500
#define TP1 (NSTEPS + 1)       // 1501 trajectory columns
#define TILE 128               // steps per lockstep tile
#define NTILE ((NSTEPS + TILE - 1) / TILE)   // 12 (last tile = 92 steps)
#define SENT 0x7fffffff

// ---------------- Threefry2x32-20 (exact JAX/Random123) ----------------
__device__ __forceinline__ void tf_block(uint32_t k0, uint32_t k1,
                                         uint32_t x0, uint32_t x1,
                                         uint32_t& o0, uint32_t& o1) {
  const uint32_t k2 = k0 ^ k1 ^ 0x1BD11BDAu;
  x0 += k0; x1 += k1;
#define TF_R(r) { x0 += x1; x1 = (x1 << (r)) | (x1 >> (32 - (r))); x1 ^= x0; }
  TF_R(13) TF_R(15) TF_R(26) TF_R(6)
  x0 += k1; x1 += k2 + 1u;
  TF_R(17) TF_R(29) TF_R(16) TF_R(24)
  x0 += k2; x1 += k0 + 2u;
  TF_R(13) TF_R(15) TF_R(26) TF_R(6)
  x0 += k0; x1 += k1 + 3u;
  TF_R(17) TF_R(29) TF_R(16) TF_R(24)
  x0 += k1; x1 += k2 + 4u;
  TF_R(13) TF_R(15) TF_R(26) TF_R(6)
  x0 += k2; x1 += k0 + 5u;
#undef TF_R
  o0 = x0; o1 = x1;
}

// bits -> uniform(-0.99999994, 1) -> sqrt(2)*erfinv, fast path (validated r10)
__device__ __forceinline__ float bits_to_normal(uint32_t bits) {
#pragma clang fp contract(off)
  const float LO = -0.99999994f;
  float f = __uint_as_float((bits >> 9) | 0x3F800000u) - 1.0f;  // [0,1)
  float u = f * 2.0f + LO;
  u = fmaxf(LO, u);
  float t = __builtin_fmaf(-u, u, 1.0f);   // 1 - u^2, single rounding
  float L = __log2f(t);                    // v_log_f32
  float p;
  if (L > -7.2134752f) {                   // w < 5
    float w = __builtin_fmaf(-0.69314718f, L, -2.5f);
    p = 3.97426059e-08f;
    p = 4.85462660e-07f + p * w;
    p = -4.98282379e-06f + p * w;
    p = -6.21053119e-06f + p * w;
    p = 3.09120051e-04f + p * w;
    p = -1.77303519e-03f + p * w;
    p = -5.90813402e-03f + p * w;
    p = 3.48802730e-01f + p * w;
    p = 2.12331454e+00f + p * w;
  } else {
    float w = sqrtf(-0.69314718f * L) - 3.0f;
    p = -2.83145880e-04f;
    p = 1.42765648e-04f + p * w;
    p = 1.90826058e-03f + p * w;
    p = -5.19501312e-03f + p * w;
    p = 8.11688966e-03f + p * w;
    p = -1.07797881e-02f + p * w;
    p = 1.33485786e-02f + p * w;
    p = 1.41658104e+00f + p * w;
    p = 4.00643424e+00f + p * w;
  }
  return p * u;   // == sqrt(2)*erfinv(u), sqrt(2) pre-folded
}

// ---------------- kernel 0: fold keys for all t ----------------
__global__ void k_fold(uint2* __restrict__ keys) {
  int t = blockIdx.x * blockDim.x + threadIdx.x;
  if (t >= NSTEPS) return;
  uint32_t o0, o1;
  tf_block(0u, 42u, 0u, (uint32_t)t, o0, o1);  // fold_in(key(42), t)
  keys[t] = make_uint2(o0, o1);
}

// ---------------- DPP 8-lane group ops ----------------
template <int CTRL>
__device__ __forceinline__ float dppf(float v) {
  int r = __builtin_amdgcn_update_dpp(0, __builtin_bit_cast(int, v), CTRL, 0xF, 0xF, true);
  return __builtin_bit_cast(float, r);
}
template <int CTRL>
__device__ __forceinline__ int dppi(int v) {
  return __builtin_amdgcn_update_dpp(0, v, CTRL, 0xF, 0xF, true);
}
// 0xB1=quad_perm[1,0,3,2](xor1) 0x4E=quad_perm[2,3,0,1](xor2)
// 0x1B=quad_perm[3,2,1,0](xor3) 0x141=row_half_mirror(xor7)

// one step, ungated (activeF==1 in live region; x1.0 is an exact identity).
// S-sum: 2 dependent DPP stages via parallel xor1/xor2/xor3 then xor7 —
// per-lane bit-identical (commuted operands only) to the validated butterfly.
#define STEP(ST, NZ)                                                    \
  {                                                                     \
    _Pragma("clang fp contract(off)")                                   \
    float x1 = dppf<0xB1>(act);                                         \
    float x2 = dppf<0x4E>(act);                                         \
    float x3 = dppf<0x1B>(act);                                         \
    float t1 = act + x1;                                                \
    float t2 = x2 + x3;                                                 \
    float Q = t1 + t2;                                                  \
    float S = Q + dppf<0x141>(Q);                                       \
    const float rec = (S * -0.1f) * 7.0f;   /* sum(act@gamma, axis=1) */\
    float a_ = inp - 0.1f * pre;                                        \
    float b_ = a_ + rec;                                                \
    pre = pre + b_ * 0.01f;                                             \
    pre = pre + (NZ) * 0.031622776601683793f; /* float(sqrt(0.001)) */  \
    act = fmaxf(pre, 0.0f);                                             \
    fc = (act >= 1.0f) ? (((ST) < fc) ? (ST) : fc) : fc;                \
    ptile[ST][lane] = pre;                                              \
  }

// ---------------- fused producer/consumer megakernel ----------------
// Block = 64 elements (8 sims), 8 waves. Wave 0: ungated recurrence ->
// LDS ptile; tile-end crossing rollback; frozen state published via
// sfroz/spre (prev-tile semantics -> race-free masked store).
// Waves 1..7: threefry noise for tile k+1 into LDS ring (rolled loop,
// 1-ahead key pipeline). Coalesced masked store each tile.
__global__ void __launch_bounds__(512) k_fused(const float* __restrict__ input,
                                               const uint2* __restrict__ keys,
                                               float* __restrict__ out) {
  __shared__ float ring[2][TILE][64];   // 64 KB noise double-buffer
  __shared__ float ptile[TILE][65];     // 33 KB pre tile (tau x e)
  __shared__ float spre[64];
  __shared__ float sfroz[64];
  __shared__ int sfz;
  const int tid = threadIdx.x;
  const int wid = tid >> 6;          // 0..7
  const int lane = tid & 63;
  const int e0 = (int)blockIdx.x << 6;
  const int e = e0 + lane;
  const size_t actoff = (size_t)NE * TP1;

  if (tid == 0) sfz = SENT;

  float pre = 0.0f, act = 0.0f, inp = 0.0f, spreR = 0.0f;
  int actv = 1;
  if (wid == 0) {
    inp = input[e];
    const size_t rowo = (size_t)e * TP1;
    out[rowo] = 0.0f;                  // tau = 0 zeros
    out[actoff + rowo] = 0.0f;
  } else {
    // prologue: produce tile 0 (rolled, 1-ahead key pipeline)
    int j = wid - 1;
    uint2 fk = keys[j];
    for (; j < TILE; j += 7) {
      const int jn = j + 7;
      uint2 fkn = (jn < TILE) ? keys[jn] : fk;
      uint32_t o0, o1;
      tf_block(fk.x, fk.y, 0u, (uint32_t)e, o0, o1);
      ring[0][j][lane] = bits_to_normal(o0 ^ o1);
      fk = fkn;
    }
  }
  __syncthreads();

  int fz = SENT;
  for (int k = 0; k < NTILE; ++k) {
    const int par = k & 1;
    const int base = k * TILE;
    const int nst = (NSTEPS - base < TILE) ? (NSTEPS - base) : TILE;
    if (wid == 0) {
      // publish frozen state as of END OF PREVIOUS tile (store reads after
      // barrier -> exactly "frozen before this tile" semantics, no race)
      sfroz[lane] = actv ? 0.0f : 1.0f;
      spre[lane] = spreR;
      int fc = TILE;   // tile-local first-crossing step (lane-local)
      if (nst == TILE) {
#pragma unroll 1
        for (int ch = 0; ch < TILE / 32; ++ch) {
          float nz[32];
#pragma unroll
          for (int j = 0; j < 32; ++j) nz[j] = ring[par][ch * 32 + j][lane];
#pragma unroll
          for (int j = 0; j < 32; ++j) STEP(ch * 32 + j, nz[j])
        }
      } else {
#pragma unroll 1
        for (int ch = 0; ch < TILE / 32; ++ch) {
          float nz[32];
#pragma unroll
          for (int j = 0; j < 32; ++j) nz[j] = ring[par][ch * 32 + j][lane];
#pragma unroll
          for (int j = 0; j < 32; ++j) {
            const int st = ch * 32 + j;
            if (st >= nst) break;
            STEP(st, nz[j])
          }
        }
      }
      // tile-end crossing resolution (off hot path)
      int c = fc;
      { int t_ = dppi<0xB1>(c);  c = (t_ < c) ? t_ : c; }
      { int t_ = dppi<0x4E>(c);  c = (t_ < c) ? t_ : c; }
      { int t_ = dppi<0x141>(c); c = (t_ < c) ? t_ : c; }
      if (actv && c < TILE) {
        const float fpre = ptile[c][lane];   // pre at crossing step (valid)
        for (int s = c + 1; s < TILE; ++s) ptile[s][lane] = fpre;
        spreR = fpre;
        actv = 0;
      }
      if (__ballot(actv != 0) == 0ull) {   // all 8 sims frozen
        spre[lane] = spreR;                // fresh values for tail fill
        if (lane == 0) sfz = base + nst + 1;
      }
    } else {
      // produce tile k+1 (rolled, 1-ahead key pipeline)
      const int nb = base + TILE;
      int j = wid - 1;
      if (nb + j < NSTEPS) {
        uint2 fk = keys[nb + j];
        for (; j < TILE && nb + j < NSTEPS; j += 7) {
          const int tn = nb + j + 7;
          uint2 fkn = (j + 7 < TILE && tn < NSTEPS) ? keys[tn] : fk;
          uint32_t o0, o1;
          tf_block(fk.x, fk.y, 0u, (uint32_t)e, o0, o1);
          ring[par ^ 1][j][lane] = bits_to_normal(o0 ^ o1);
          fk = fkn;
        }
      }
    }
    __syncthreads();
    // masked coalesced store: wave w owns e-rows w*8..w*8+7, lanes = tau
    {
      float fm[8], sv[8];
#pragma unroll
      for (int ee = 0; ee < 8; ++ee) {
        const int el = (wid << 3) + ee;
        fm[ee] = sfroz[el];
        sv[ee] = spre[el];
      }
#pragma unroll
      for (int tb = 0; tb < TILE / 64; ++tb) {
        const int ln = nst - tb * 64;
        if (lane < ln) {
          const int tau = base + 1 + tb * 64 + lane;
#pragma unroll
          for (int ee = 0; ee < 8; ++ee) {
            const int el = (wid << 3) + ee;
            float p = ptile[tb * 64 + lane][el];
            p = (fm[ee] > 0.0f) ? sv[ee] : p;
            const size_t o = (size_t)(e0 + el) * TP1 + (size_t)tau;
            out[o] = p;
            out[actoff + o] = fmaxf(p, 0.0f);   // act == relu(pre)
          }
        }
      }
    }
    if (sfz != SENT) { fz = sfz; break; }   // uniform exit (read after barrier)
    __syncthreads();                        // protect ptile/ring reuse
  }

  if (fz <= NSTEPS) {
    // post-freeze constant tail, coalesced (lanes over tau)
#pragma unroll
    for (int ee = 0; ee < 8; ++ee) {
      const int el = (wid << 3) + ee;
      const float p = spre[el];
      const float a = fmaxf(p, 0.0f);
      const size_t ro = (size_t)(e0 + el) * TP1;
      for (int tau = fz + lane; tau <= NSTEPS; tau += 64) {
        out[ro + (size_t)tau] = p;
        out[actoff + ro + (size_t)tau] = a;
      }
    }
  }
}

extern "C" void kernel_launch(void* const* d_in, const int* in_sizes, int n_in,
                              void* d_out, int out_size, void* d_ws, size_t ws_size,
                              hipStream_t stream) {
  const float* input = (const float*)d_in[0];
  float* out = (float*)d_out;
  uint2* keys = (uint2*)d_ws;   // 1500 * 8 B = 12 KB
  if (ws_size < NSTEPS * sizeof(uint2)) return;

  k_fold<<<dim3((NSTEPS + 255) / 256), dim3(256), 0, stream>>>(keys);
  k_fused<<<dim3(NSIMS / 8), dim3(512), 0, stream>>>(input, keys, out);
}